// Round 4
// baseline (475.219 us; speedup 1.0000x reference)
//
#include <hip/hip_runtime.h>
#include <hip/hip_bf16.h>
#include <math.h>

#define N_NODES 100000
#define N_EDGES 1600000
#define HID 128
#define D_IN 6
#define NEG_SLOPE 0.2f

#define NB_BKT 128            // nodes per bucket
#define NBKT 782              // ceil(N_NODES / NB_BKT)
#define SUBS 8                // sub-buffers per bucket (pseudo-XCD)
#define CAPS 384              // capacity per (bucket, sub): mean 256 + 8 sigma
#define S2_CAP 3072           // max edges per bucket (mean 2048 + 22 sigma)

// ---------------------------------------------------------------------------
// K_prep (1 block): w_as = w_gat@att_src (6), w_ad = w_gat@att_dst (6),
// dotwe = w_edge . att_edge
__global__ __launch_bounds__(128) void k_prep(
    const float* __restrict__ w_gat, const float* __restrict__ att_src,
    const float* __restrict__ att_dst, const float* __restrict__ w_edge,
    const float* __restrict__ att_edge, float* __restrict__ w_as,
    float* __restrict__ w_ad, float* __restrict__ dotwe)
{
    int tid = threadIdx.x;
    __shared__ float red[4];
    float as = att_src[tid], ad = att_dst[tid];

    float v = w_edge[tid] * att_edge[tid];
    for (int o = 32; o; o >>= 1) v += __shfl_down(v, o);
    if ((tid & 63) == 0) red[tid >> 6] = v;
    __syncthreads();
    if (tid == 0) dotwe[0] = red[0] + red[1];

#pragma unroll
    for (int i = 0; i < D_IN; ++i) {
        float wv = w_gat[i * HID + tid];
        float v1 = wv * as, v2 = wv * ad;
        for (int o = 32; o; o >>= 1) {
            v1 += __shfl_down(v1, o);
            v2 += __shfl_down(v2, o);
        }
        __syncthreads();
        if ((tid & 63) == 0) { red[(tid >> 6) * 2] = v1; red[(tid >> 6) * 2 + 1] = v2; }
        __syncthreads();
        if (tid == 0) { w_as[i] = red[0] + red[2]; w_ad[i] = red[1] + red[3]; }
    }
}

// ---------------------------------------------------------------------------
__global__ __launch_bounds__(256) void k_asrc(
    const float* __restrict__ x, const float* __restrict__ w_as,
    const float* __restrict__ w_ad, float* __restrict__ a_src,
    float* __restrict__ a_dst)
{
    int n = blockIdx.x * 256 + threadIdx.x;
    if (n >= N_NODES) return;
    float s0 = 0.f, s1 = 0.f;
#pragma unroll
    for (int i = 0; i < D_IN; ++i) {
        float xv = x[n * D_IN + i];
        s0 += xv * w_as[i];
        s1 += xv * w_ad[i];
    }
    a_src[n] = s0;
    a_dst[n] = s1;
}

// ---------------------------------------------------------------------------
// K_edge1: coalesced edge pass. p = exp(leaky(logit)) (no max-subtraction:
// |logit| <~ 3 so exp is safe; alpha identical to max-subtracted form).
// Accumulates denom and in-degree via L2-resident atomics.
__global__ __launch_bounds__(256) void k_edge1(
    const int* __restrict__ src, const int* __restrict__ dst,
    const float* __restrict__ ew, const float* __restrict__ a_src,
    const float* __restrict__ a_dst, const float* __restrict__ dotwe,
    float* __restrict__ p_arr, float* __restrict__ denom, int* __restrict__ cnt)
{
    int e = blockIdx.x * 256 + threadIdx.x;
    if (e >= N_EDGES) return;
    int s = src[e], d = dst[e];
    float lg = a_src[s] + a_dst[d] + dotwe[0] * ew[e];
    lg = (lg >= 0.f) ? lg : NEG_SLOPE * lg;
    float p = __expf(lg);
    p_arr[e] = p;
    atomicAdd(&denom[d], p);
    atomicAdd(&cnt[d], 1);
}

// ---------------------------------------------------------------------------
// exclusive prefix sum of cnt[N] -> off[N+1]
__global__ __launch_bounds__(256) void k_scan1(
    const int* __restrict__ cnt, int* __restrict__ incl, int* __restrict__ bsums)
{
    __shared__ int s[256];
    int tid = threadIdx.x;
    int i = blockIdx.x * 256 + tid;
    int v = (i < N_NODES) ? cnt[i] : 0;
    s[tid] = v;
    __syncthreads();
    for (int o = 1; o < 256; o <<= 1) {
        int t = (tid >= o) ? s[tid - o] : 0;
        __syncthreads();
        s[tid] += t;
        __syncthreads();
    }
    if (i < N_NODES) incl[i] = s[tid];
    if (tid == 255) bsums[blockIdx.x] = s[255];
}

__global__ __launch_bounds__(512) void k_scan2(
    const int* __restrict__ bsums, int* __restrict__ boffs, int nb)
{
    __shared__ int s[512];
    int tid = threadIdx.x;
    int v = (tid < nb) ? bsums[tid] : 0;
    s[tid] = v;
    __syncthreads();
    for (int o = 1; o < 512; o <<= 1) {
        int t = (tid >= o) ? s[tid - o] : 0;
        __syncthreads();
        s[tid] += t;
        __syncthreads();
    }
    if (tid < nb) boffs[tid] = s[tid] - v;  // exclusive
}

__global__ __launch_bounds__(256) void k_scan3(
    const int* __restrict__ cnt, const int* __restrict__ incl,
    const int* __restrict__ boffs, int* __restrict__ off)
{
    int i = blockIdx.x * 256 + threadIdx.x;
    if (i < N_NODES) {
        int b = boffs[blockIdx.x];
        off[i] = b + incl[i] - cnt[i];
        if (i == N_NODES - 1) off[N_NODES] = b + incl[i];
    }
}

// ---------------------------------------------------------------------------
// K_s1: coalesced edge pass: alpha = p/denom[d]; write alpha_out (original
// order, coalesced); append record {dl<<17|src, alpha} to the (bucket, sub)
// buffer. sub = blockIdx&7 keeps appenders (heuristically) XCD-local and
// temporally adjacent -> write-combining in L2.
__global__ __launch_bounds__(256) void k_s1(
    const int* __restrict__ src, const int* __restrict__ dst,
    const float* __restrict__ p_arr, const float* __restrict__ denom,
    int* __restrict__ bcnt, uint2* __restrict__ bucket_buf,
    float* __restrict__ alpha_out)
{
    int e = blockIdx.x * 256 + threadIdx.x;
    if (e >= N_EDGES) return;
    int d = dst[e], s = src[e];
    float a = p_arr[e] / fmaxf(denom[d], 1e-16f);
    alpha_out[e] = a;
    int b = d >> 7, dl = d & 127;
    int slot = b * SUBS + (blockIdx.x & 7);
    int pos = atomicAdd(&bcnt[slot], 1);
    if (pos >= CAPS) pos = CAPS - 1;   // 8-sigma guard, never in practice
    uint2 r;
    r.x = ((unsigned)dl << 17) | (unsigned)s;
    r.y = __float_as_uint(a);
    bucket_buf[(size_t)slot * CAPS + pos] = r;
}

// ---------------------------------------------------------------------------
// K_s2: one block per bucket (128 nodes). LDS counting-sort of the bucket's
// records using global off[] as the base; linear coalesced CSR write; xagg
// (6-dim weighted x sum + dinv flag) computed from the LDS-resident segments.
__global__ __launch_bounds__(256) void k_s2(
    const int* __restrict__ off, const int* __restrict__ bcnt,
    const uint2* __restrict__ bucket_buf, const float* __restrict__ x,
    uint2* __restrict__ sa_srt, float* __restrict__ xagg8)
{
    __shared__ uint2 srt[S2_CAP];
    __shared__ int base_l[NB_BKT + 1];
    __shared__ int fill_l[NB_BKT];
    int b = blockIdx.x, tid = threadIdx.x;
    int nb0 = b * NB_BKT;
    int g0 = off[nb0];
    if (tid <= NB_BKT) {
        int idx = nb0 + tid;
        if (idx > N_NODES) idx = N_NODES;
        base_l[tid] = off[idx] - g0;
    }
    if (tid < NB_BKT) fill_l[tid] = 0;
    __syncthreads();
    int T = base_l[NB_BKT];

    for (int k = 0; k < SUBS; ++k) {
        int slot = b * SUBS + k;
        int len = bcnt[slot];
        const uint2* buf = bucket_buf + (size_t)slot * CAPS;
        for (int i = tid; i < len; i += 256) {
            uint2 r = buf[i];                        // coalesced
            int dl = r.x >> 17;
            int lp = base_l[dl] + atomicAdd(&fill_l[dl], 1);
            if (lp < S2_CAP)
                srt[lp] = make_uint2(r.x & 0x1FFFFu, r.y);
        }
    }
    __syncthreads();

    // coalesced CSR write
    for (int i = tid; i < T; i += 256) sa_srt[g0 + i] = srt[i];

    // xagg: one thread per node, segment is LDS-resident
    if (tid < NB_BKT) {
        int n = nb0 + tid;
        if (n < N_NODES) {
            int s0 = base_l[tid], s1 = base_l[tid + 1];
            float ax0 = 0, ax1 = 0, ax2 = 0, ax3 = 0, ax4 = 0, ax5 = 0;
            for (int j = s0; j < s1; ++j) {
                uint2 r = srt[j];
                float a = __uint_as_float(r.y);
                const float2* xp = (const float2*)(x + (size_t)r.x * D_IN);
                float2 q0 = xp[0], q1 = xp[1], q2 = xp[2];
                ax0 += a * q0.x; ax1 += a * q0.y; ax2 += a * q1.x;
                ax3 += a * q1.y; ax4 += a * q2.x; ax5 += a * q2.y;
            }
            float dv = (s1 > s0) ? 1.0f : 0.0f;   // sum(alpha)=1 -> dinv=1
            float* xo = xagg8 + (size_t)n * 8;
            float4 lo = {dv, ax0, ax1, ax2};
            float4 hi = {ax3, ax4, ax5, 0.f};
            *(float4*)xo = lo;
            *(float4*)(xo + 4) = hi;
        }
    }
}

// ---------------------------------------------------------------------------
// K_gcn_gather (2-phase): 4 nodes/block.
// P1: lane-per-edge parallel gather of {dinv_s*alpha, xagg[0..5]} -> LDS.
// P2: wave-per-node, 2 features/lane, broadcast ds_read_b128, per-feature acc.
#define GCAP 128
__global__ __launch_bounds__(256) void k_gcn_gather(
    const uint2* __restrict__ sa_srt, const int* __restrict__ off,
    const float* __restrict__ xagg8, const float* __restrict__ w_gat,
    const float* __restrict__ b_gat, float* __restrict__ agg)
{
    __shared__ float lds[GCAP * 12];
    int tid = threadIdx.x;
    int n0 = blockIdx.x * 4;
    int wid = tid >> 6, l = tid & 63;
    int n = n0 + wid;
    int beg0 = off[n0];
    int total = off[n0 + 4] - beg0;
    int nb = off[n] - beg0, ne = off[n + 1] - beg0;

    int kA = l, kB = l + 64;
    float wA0 = w_gat[0 * HID + kA], wA1 = w_gat[1 * HID + kA], wA2 = w_gat[2 * HID + kA];
    float wA3 = w_gat[3 * HID + kA], wA4 = w_gat[4 * HID + kA], wA5 = w_gat[5 * HID + kA];
    float wB0 = w_gat[0 * HID + kB], wB1 = w_gat[1 * HID + kB], wB2 = w_gat[2 * HID + kB];
    float wB3 = w_gat[3 * HID + kB], wB4 = w_gat[4 * HID + kB], wB5 = w_gat[5 * HID + kB];
    float bA = b_gat[kA], bB = b_gat[kB];
    float accA = 0.f, accB = 0.f;

    for (int base = 0; base < total; base += GCAP) {
        int cnt = min(GCAP, total - base);
        __syncthreads();
        if (tid < cnt) {
            int j = beg0 + base + tid;
            uint2 sa = sa_srt[j];                  // coalesced 8B
            float a = __uint_as_float(sa.y);
            const float4* xp = (const float4*)(xagg8 + (size_t)sa.x * 8);
            float4 lo = xp[0], hi = xp[1];         // {dinv_s,x0,x1,x2},{x3,x4,x5,-}
            float4 w0 = {lo.x * a, lo.y, lo.z, lo.w};
            float4 w1 = {hi.x, hi.y, hi.z, 0.f};
            *(float4*)(lds + tid * 12) = w0;
            *(float4*)(lds + tid * 12 + 4) = w1;
        }
        __syncthreads();
        int lo_t = nb - base; if (lo_t < 0) lo_t = 0;
        int hi_t = ne - base; if (hi_t > cnt) hi_t = cnt;
        for (int t = lo_t; t < hi_t; ++t) {
            float4 e0 = *(const float4*)(lds + t * 12);
            float4 e1 = *(const float4*)(lds + t * 12 + 4);
            float hA = bA, hB = bB;
            hA = fmaf(e0.y, wA0, hA); hB = fmaf(e0.y, wB0, hB);
            hA = fmaf(e0.z, wA1, hA); hB = fmaf(e0.z, wB1, hB);
            hA = fmaf(e0.w, wA2, hA); hB = fmaf(e0.w, wB2, hB);
            hA = fmaf(e1.x, wA3, hA); hB = fmaf(e1.x, wB3, hB);
            hA = fmaf(e1.y, wA4, hA); hB = fmaf(e1.y, wB4, hB);
            hA = fmaf(e1.z, wA5, hA); hB = fmaf(e1.z, wB5, hB);
            hA = fmaxf(hA, 0.f); hB = fmaxf(hB, 0.f);
            accA = fmaf(e0.x, hA, accA); accB = fmaf(e0.x, hB, accB);
        }
    }
    float dn = xagg8[(size_t)n * 8];
    agg[(size_t)n * HID + kA] = dn * accA;
    agg[(size_t)n * HID + kB] = dn * accB;
}

// ---------------------------------------------------------------------------
// K_dense2: h2 = relu(agg @ w_gcn + b_gcn); out = h2 @ w_out + b_out
#define NPB 32
#define HSTR (NPB + 4)
__global__ __launch_bounds__(128) void k_dense2(
    const float* __restrict__ agg, const float* __restrict__ w_gcn,
    const float* __restrict__ b_gcn, const float* __restrict__ w_out,
    const float* __restrict__ b_out, float* __restrict__ out)
{
    __shared__ float hsT[HID][HSTR];
    __shared__ float red[2][64];
    int n0 = blockIdx.x * NPB;
    int tid = threadIdx.x;

#pragma unroll
    for (int r = 0; r < NPB; ++r)
        hsT[tid][r] = agg[(size_t)(n0 + r) * HID + tid];
    __syncthreads();

    float acc[NPB];
#pragma unroll
    for (int r = 0; r < NPB; ++r) acc[r] = 0.f;
    for (int i = 0; i < HID; ++i) {
        float wv = w_gcn[i * HID + tid];
        const float4* hp = (const float4*)&hsT[i][0];
#pragma unroll
        for (int r4 = 0; r4 < NPB / 4; ++r4) {
            float4 hv = hp[r4];
            acc[r4 * 4 + 0] += hv.x * wv;
            acc[r4 * 4 + 1] += hv.y * wv;
            acc[r4 * 4 + 2] += hv.z * wv;
            acc[r4 * 4 + 3] += hv.w * wv;
        }
    }
    __syncthreads();

    float b = b_gcn[tid];
#pragma unroll
    for (int r = 0; r < NPB; ++r)
        hsT[tid][r] = fmaxf(acc[r] + b, 0.f);   // h2, transposed
    __syncthreads();

    int r = tid & 31, o = (tid >> 5) & 1, half = tid >> 6;
    float v = 0.f;
    for (int k = half * 64; k < half * 64 + 64; ++k)
        v += hsT[k][r] * w_out[k * 2 + o];
    red[half][tid & 63] = v;
    __syncthreads();
    if (tid < 64) {
        float t = red[0][tid] + red[1][tid];
        int rr = tid & 31, oo = tid >> 5;
        out[(size_t)(n0 + rr) * 2 + oo] = t + b_out[oo];
    }
}

// ---------------------------------------------------------------------------
__global__ __launch_bounds__(256) void k_copy_ei(
    const int* __restrict__ ei, float* __restrict__ out_ei)
{
    int i = blockIdx.x * 256 + threadIdx.x;
    if (i < 2 * N_EDGES) out_ei[i] = (float)ei[i];
}

// ---------------------------------------------------------------------------
extern "C" void kernel_launch(void* const* d_in, const int* in_sizes, int n_in,
                              void* d_out, int out_size, void* d_ws, size_t ws_size,
                              hipStream_t stream)
{
    const float* x        = (const float*)d_in[0];
    const int*   ei       = (const int*)d_in[1];
    const float* ew       = (const float*)d_in[2];
    const float* w_gat    = (const float*)d_in[3];
    const float* att_src  = (const float*)d_in[4];
    const float* att_dst  = (const float*)d_in[5];
    const float* w_edge   = (const float*)d_in[6];
    const float* att_edge = (const float*)d_in[7];
    const float* b_gat    = (const float*)d_in[8];
    const float* w_gcn    = (const float*)d_in[9];
    const float* b_gcn    = (const float*)d_in[10];
    const float* w_out    = (const float*)d_in[11];
    const float* b_out    = (const float*)d_in[12];

    const int* src = ei;
    const int* dst = ei + N_EDGES;

    float* out_head  = (float*)d_out;
    float* out_ei    = out_head + 2 * N_NODES;
    float* out_alpha = out_ei + 2 * N_EDGES;

    char* ws = (char*)d_ws;
    size_t o = 0;
    auto alloc = [&](size_t bytes) -> char* {
        char* p = ws + o;
        o = (o + bytes + 255) & ~(size_t)255;
        return p;
    };
    float* agg        = (float*)alloc((size_t)N_NODES * HID * 4);          // 51.2 MB
    uint2* bucket_buf = (uint2*)alloc((size_t)NBKT * SUBS * CAPS * 8);     // 19.2 MB
    uint2* sa_srt     = (uint2*)alloc((size_t)N_EDGES * 8);                // 12.8 MB
    float* p_arr      = (float*)alloc((size_t)N_EDGES * 4);                // 6.4 MB
    float* xagg8      = (float*)alloc((size_t)N_NODES * 8 * 4);            // 3.2 MB
    float* a_src      = (float*)alloc(N_NODES * 4);
    float* a_dst      = (float*)alloc(N_NODES * 4);
    float* denom      = (float*)alloc(N_NODES * 4);
    int*   cnt        = (int*)alloc(N_NODES * 4);
    int*   incl       = (int*)alloc(N_NODES * 4);
    int*   off        = (int*)alloc((N_NODES + 1) * 4);
    int*   bsums      = (int*)alloc(512 * 4);
    int*   boffs      = (int*)alloc(512 * 4);
    int*   bcnt       = (int*)alloc(NBKT * SUBS * 4);
    float* w_as       = (float*)alloc(D_IN * 4);
    float* w_ad       = (float*)alloc(D_IN * 4);
    float* dotwe      = (float*)alloc(4);
    (void)ws_size; (void)out_size; (void)n_in; (void)in_sizes;

    hipMemsetAsync(cnt, 0, N_NODES * 4, stream);
    hipMemsetAsync(denom, 0, N_NODES * 4, stream);
    hipMemsetAsync(bcnt, 0, NBKT * SUBS * 4, stream);

    const int NB_SCAN = (N_NODES + 255) / 256;   // 391
    const int NB_EDGE = (N_EDGES + 255) / 256;   // 6250

    k_prep<<<1, 128, 0, stream>>>(w_gat, att_src, att_dst, w_edge, att_edge,
                                  w_as, w_ad, dotwe);
    k_asrc<<<NB_SCAN, 256, 0, stream>>>(x, w_as, w_ad, a_src, a_dst);
    k_edge1<<<NB_EDGE, 256, 0, stream>>>(src, dst, ew, a_src, a_dst, dotwe,
                                         p_arr, denom, cnt);
    k_scan1<<<NB_SCAN, 256, 0, stream>>>(cnt, incl, bsums);
    k_scan2<<<1, 512, 0, stream>>>(bsums, boffs, NB_SCAN);
    k_scan3<<<NB_SCAN, 256, 0, stream>>>(cnt, incl, boffs, off);
    k_s1<<<NB_EDGE, 256, 0, stream>>>(src, dst, p_arr, denom,
                                      bcnt, bucket_buf, out_alpha);
    k_s2<<<NBKT, 256, 0, stream>>>(off, bcnt, bucket_buf, x, sa_srt, xagg8);
    k_gcn_gather<<<N_NODES / 4, 256, 0, stream>>>(
        sa_srt, off, xagg8, w_gat, b_gat, agg);
    k_dense2<<<N_NODES / NPB, 128, 0, stream>>>(
        agg, w_gcn, b_gcn, w_out, b_out, out_head);
    k_copy_ei<<<(2 * N_EDGES + 255) / 256, 256, 0, stream>>>(ei, out_ei);
}

// Round 5
// 307.966 us; speedup vs baseline: 1.5431x; 1.5431x over previous
//
#include <hip/hip_runtime.h>
#include <hip/hip_bf16.h>
#include <math.h>

#define N_NODES 100000
#define N_EDGES 1600000
#define HID 128
#define D_IN 6
#define NEG_SLOPE 0.2f

#define NB_BKT 128                       // nodes per bucket
#define NBKT 782                         // ceil(N_NODES / NB_BKT)
#define NBLK_P 200                       // partition blocks
#define EPB ((N_EDGES + NBLK_P - 1) / NBLK_P)   // 8000 edges per partition block
#define NHIST (NBKT * NBLK_P)            // 156400
#define S2_CAP 3072                      // max edges per bucket (mean 2048, +22 sigma)

// ---------------------------------------------------------------------------
// K_prep (1 block): w_as = w_gat@att_src (6), w_ad = w_gat@att_dst (6),
// dotwe = w_edge . att_edge
__global__ __launch_bounds__(128) void k_prep(
    const float* __restrict__ w_gat, const float* __restrict__ att_src,
    const float* __restrict__ att_dst, const float* __restrict__ w_edge,
    const float* __restrict__ att_edge, float* __restrict__ w_as,
    float* __restrict__ w_ad, float* __restrict__ dotwe)
{
    int tid = threadIdx.x;
    __shared__ float red[4];
    float as = att_src[tid], ad = att_dst[tid];

    float v = w_edge[tid] * att_edge[tid];
    for (int o = 32; o; o >>= 1) v += __shfl_down(v, o);
    if ((tid & 63) == 0) red[tid >> 6] = v;
    __syncthreads();
    if (tid == 0) dotwe[0] = red[0] + red[1];

#pragma unroll
    for (int i = 0; i < D_IN; ++i) {
        float wv = w_gat[i * HID + tid];
        float v1 = wv * as, v2 = wv * ad;
        for (int o = 32; o; o >>= 1) {
            v1 += __shfl_down(v1, o);
            v2 += __shfl_down(v2, o);
        }
        __syncthreads();
        if ((tid & 63) == 0) { red[(tid >> 6) * 2] = v1; red[(tid >> 6) * 2 + 1] = v2; }
        __syncthreads();
        if (tid == 0) { w_as[i] = red[0] + red[2]; w_ad[i] = red[1] + red[3]; }
    }
}

// ---------------------------------------------------------------------------
__global__ __launch_bounds__(256) void k_asrc(
    const float* __restrict__ x, const float* __restrict__ w_as,
    const float* __restrict__ w_ad, float* __restrict__ a_src,
    float* __restrict__ a_dst)
{
    int n = blockIdx.x * 256 + threadIdx.x;
    if (n >= N_NODES) return;
    float s0 = 0.f, s1 = 0.f;
#pragma unroll
    for (int i = 0; i < D_IN; ++i) {
        float xv = x[n * D_IN + i];
        s0 += xv * w_as[i];
        s1 += xv * w_ad[i];
    }
    a_src[n] = s0;
    a_dst[n] = s1;
}

// ---------------------------------------------------------------------------
// K_hist: per-block LDS histogram over dst-buckets (no device atomics)
__global__ __launch_bounds__(256) void k_hist(
    const int* __restrict__ dst, int* __restrict__ histG)
{
    __shared__ int h[NBKT];
    for (int b = threadIdx.x; b < NBKT; b += 256) h[b] = 0;
    __syncthreads();
    int e0 = blockIdx.x * EPB, e1 = min(e0 + EPB, N_EDGES);
    for (int e = e0 + threadIdx.x; e < e1; e += 256)
        atomicAdd(&h[dst[e] >> 7], 1);           // LDS atomic (CU-local)
    __syncthreads();
    for (int b = threadIdx.x; b < NBKT; b += 256)
        histG[b * NBLK_P + blockIdx.x] = h[b];   // bucket-major layout
}

// ---------------------------------------------------------------------------
// generic exclusive scan (3 kernels, 512-thread blocks), n arbitrary
__global__ __launch_bounds__(512) void k_scan1(
    const int* __restrict__ in, int* __restrict__ incl, int* __restrict__ bsums,
    int n)
{
    __shared__ int s[512];
    int tid = threadIdx.x;
    int i = blockIdx.x * 512 + tid;
    int v = (i < n) ? in[i] : 0;
    s[tid] = v;
    __syncthreads();
    for (int o = 1; o < 512; o <<= 1) {
        int t = (tid >= o) ? s[tid - o] : 0;
        __syncthreads();
        s[tid] += t;
        __syncthreads();
    }
    if (i < n) incl[i] = s[tid];
    if (tid == 511) bsums[blockIdx.x] = s[511];
}

__global__ __launch_bounds__(512) void k_scan2(
    const int* __restrict__ bsums, int* __restrict__ boffs, int nb)
{
    __shared__ int s[512];
    int tid = threadIdx.x;
    int v = (tid < nb) ? bsums[tid] : 0;
    s[tid] = v;
    __syncthreads();
    for (int o = 1; o < 512; o <<= 1) {
        int t = (tid >= o) ? s[tid - o] : 0;
        __syncthreads();
        s[tid] += t;
        __syncthreads();
    }
    if (tid < nb) boffs[tid] = s[tid] - v;  // exclusive
}

__global__ __launch_bounds__(512) void k_scan3(
    const int* __restrict__ in, const int* __restrict__ incl,
    const int* __restrict__ boffs, int* __restrict__ off, int n)
{
    int i = blockIdx.x * 512 + threadIdx.x;
    if (i < n) {
        int b = boffs[blockIdx.x];
        off[i] = b + incl[i] - in[i];
        if (i == n - 1) off[n] = b + incl[i];
    }
}

// ---------------------------------------------------------------------------
// K_part: stable partition into dst-buckets. Each (block,bucket) writes into
// its exclusive range [offP[b*200+blk], ...) via an LDS cursor -> no device
// atomics; block-private regions stay L2-resident (low write-amp).
// Also computes p = exp(leaky(logit)) and stores p_arr (original order).
__global__ __launch_bounds__(256) void k_part(
    const int* __restrict__ src, const int* __restrict__ dst,
    const float* __restrict__ ew, const float* __restrict__ a_src,
    const float* __restrict__ a_dst, const float* __restrict__ dotwe,
    const int* __restrict__ offP, float* __restrict__ p_arr,
    uint2* __restrict__ rec)
{
    __shared__ int curs[NBKT];
    for (int b = threadIdx.x; b < NBKT; b += 256)
        curs[b] = offP[b * NBLK_P + blockIdx.x];
    __syncthreads();
    float dw = dotwe[0];
    int e0 = blockIdx.x * EPB, e1 = min(e0 + EPB, N_EDGES);
    for (int e = e0 + threadIdx.x; e < e1; e += 256) {
        int d = dst[e], s = src[e];
        float lg = a_src[s] + a_dst[d] + dw * ew[e];
        lg = (lg >= 0.f) ? lg : NEG_SLOPE * lg;
        float p = __expf(lg);
        p_arr[e] = p;
        int pos = atomicAdd(&curs[d >> 7], 1);   // LDS atomic
        rec[pos] = make_uint2(((unsigned)(d & 127) << 17) | (unsigned)s,
                              __float_as_uint(p));
    }
}

// ---------------------------------------------------------------------------
// K_s2: one block per bucket. LDS counting-sort (local bases via LDS scan),
// per-node denom, alpha normalize, coalesced CSR writeout, xagg, off, denomG.
__global__ __launch_bounds__(256) void k_s2(
    const int* __restrict__ offP, const uint2* __restrict__ rec,
    const float* __restrict__ x, uint2* __restrict__ sa_srt,
    float* __restrict__ xagg8, float* __restrict__ denomG,
    int* __restrict__ off)
{
    __shared__ uint2 srt[S2_CAP];
    __shared__ int cntL[NB_BKT], fillL[NB_BKT], baseL[NB_BKT + 1];
    __shared__ int sc[NB_BKT];
    __shared__ float rden[NB_BKT];
    int b = blockIdx.x, tid = threadIdx.x;
    int g0 = offP[b * NBLK_P];
    int g1 = offP[(b + 1) * NBLK_P];     // b==NBKT-1 -> offP[NHIST] == N_EDGES
    int len = min(g1 - g0, S2_CAP);

    if (tid < NB_BKT) { cntL[tid] = 0; fillL[tid] = 0; }
    __syncthreads();

    // pass 1: count (records re-read from L2)
    for (int i = tid; i < len; i += 256)
        atomicAdd(&cntL[rec[g0 + i].x >> 17], 1);
    __syncthreads();

    // LDS scan over 128 counts -> baseL (exclusive)
    {
        int v = (tid < NB_BKT) ? cntL[tid] : 0;
        if (tid < NB_BKT) sc[tid] = v;
        __syncthreads();
        for (int o = 1; o < NB_BKT; o <<= 1) {
            int t = (tid >= o && tid < NB_BKT) ? sc[tid - o] : 0;
            __syncthreads();
            if (tid < NB_BKT) sc[tid] += t;
            __syncthreads();
        }
        if (tid < NB_BKT) baseL[tid + 1] = sc[tid];
        if (tid == 0) baseL[0] = 0;
    }
    __syncthreads();

    // pass 2: place into sorted LDS order
    for (int i = tid; i < len; i += 256) {
        uint2 r = rec[g0 + i];
        int dl = r.x >> 17;
        int p = baseL[dl] + atomicAdd(&fillL[dl], 1);
        if (p < S2_CAP) srt[p] = r;
    }
    __syncthreads();

    // per-node denom
    if (tid < NB_BKT) {
        int s0 = baseL[tid], s1 = baseL[tid + 1];
        float dsum = 0.f;
        for (int j = s0; j < s1; ++j) dsum += __uint_as_float(srt[j].y);
        int n = b * NB_BKT + tid;
        if (n < N_NODES) denomG[n] = dsum;
        rden[tid] = 1.0f / fmaxf(dsum, 1e-16f);
    }
    __syncthreads();

    // normalize alpha in LDS + coalesced CSR writeout {src, alpha}
    for (int i = tid; i < len; i += 256) {
        uint2 r = srt[i];
        int dl = r.x >> 17;
        float a = __uint_as_float(r.y) * rden[dl];
        srt[i].y = __float_as_uint(a);
        sa_srt[g0 + i] = make_uint2(r.x & 0x1FFFFu, __float_as_uint(a));
    }
    __syncthreads();

    // xagg (6-dim weighted x sum) + off
    if (tid < NB_BKT) {
        int n = b * NB_BKT + tid;
        if (n < N_NODES) {
            int s0 = baseL[tid], s1 = baseL[tid + 1];
            float ax0 = 0, ax1 = 0, ax2 = 0, ax3 = 0, ax4 = 0, ax5 = 0;
            for (int j = s0; j < s1; ++j) {
                uint2 r = srt[j];
                float a = __uint_as_float(r.y);
                const float2* xp = (const float2*)(x + (size_t)(r.x & 0x1FFFFu) * D_IN);
                float2 q0 = xp[0], q1 = xp[1], q2 = xp[2];
                ax0 += a * q0.x; ax1 += a * q0.y; ax2 += a * q1.x;
                ax3 += a * q1.y; ax4 += a * q2.x; ax5 += a * q2.y;
            }
            float dv = (s1 > s0) ? 1.0f : 0.0f;   // sum(alpha)=1 -> dinv=1
            float* xo = xagg8 + (size_t)n * 8;
            float4 lo = {dv, ax0, ax1, ax2};
            float4 hi = {ax3, ax4, ax5, 0.f};
            *(float4*)xo = lo;
            *(float4*)(xo + 4) = hi;
            off[n] = g0 + s0;
        }
    }
    if (b == NBKT - 1 && tid == 0) off[N_NODES] = g1;
}

// ---------------------------------------------------------------------------
// K_alpha: original-order alpha output (coalesced; denom gathered, L3-resident)
__global__ __launch_bounds__(256) void k_alpha(
    const float* __restrict__ p_arr, const int* __restrict__ dst,
    const float* __restrict__ denomG, float* __restrict__ alpha_out)
{
    int e = blockIdx.x * 256 + threadIdx.x;
    if (e >= N_EDGES) return;
    alpha_out[e] = p_arr[e] / fmaxf(denomG[dst[e]], 1e-16f);
}

// ---------------------------------------------------------------------------
// K_gcn_gather (2-phase): 4 nodes/block.
// P1: lane-per-edge parallel gather of {dinv_s*alpha, xagg[0..5]} -> LDS.
// P2: wave-per-node, 2 features/lane, broadcast ds_read_b128, per-feature acc.
#define GCAP 128
__global__ __launch_bounds__(256) void k_gcn_gather(
    const uint2* __restrict__ sa_srt, const int* __restrict__ off,
    const float* __restrict__ xagg8, const float* __restrict__ w_gat,
    const float* __restrict__ b_gat, float* __restrict__ agg)
{
    __shared__ float lds[GCAP * 12];
    int tid = threadIdx.x;
    int n0 = blockIdx.x * 4;
    int wid = tid >> 6, l = tid & 63;
    int n = n0 + wid;
    int beg0 = off[n0];
    int total = off[n0 + 4] - beg0;
    int nb = off[n] - beg0, ne = off[n + 1] - beg0;

    int kA = l, kB = l + 64;
    float wA0 = w_gat[0 * HID + kA], wA1 = w_gat[1 * HID + kA], wA2 = w_gat[2 * HID + kA];
    float wA3 = w_gat[3 * HID + kA], wA4 = w_gat[4 * HID + kA], wA5 = w_gat[5 * HID + kA];
    float wB0 = w_gat[0 * HID + kB], wB1 = w_gat[1 * HID + kB], wB2 = w_gat[2 * HID + kB];
    float wB3 = w_gat[3 * HID + kB], wB4 = w_gat[4 * HID + kB], wB5 = w_gat[5 * HID + kB];
    float bA = b_gat[kA], bB = b_gat[kB];
    float accA = 0.f, accB = 0.f;

    for (int base = 0; base < total; base += GCAP) {
        int cnt = min(GCAP, total - base);
        __syncthreads();
        if (tid < cnt) {
            int j = beg0 + base + tid;
            uint2 sa = sa_srt[j];                  // coalesced 8B
            float a = __uint_as_float(sa.y);
            const float4* xp = (const float4*)(xagg8 + (size_t)sa.x * 8);
            float4 lo = xp[0], hi = xp[1];         // {dinv_s,x0,x1,x2},{x3,x4,x5,-}
            float4 w0 = {lo.x * a, lo.y, lo.z, lo.w};
            float4 w1 = {hi.x, hi.y, hi.z, 0.f};
            *(float4*)(lds + tid * 12) = w0;
            *(float4*)(lds + tid * 12 + 4) = w1;
        }
        __syncthreads();
        int lo_t = nb - base; if (lo_t < 0) lo_t = 0;
        int hi_t = ne - base; if (hi_t > cnt) hi_t = cnt;
        for (int t = lo_t; t < hi_t; ++t) {
            float4 e0 = *(const float4*)(lds + t * 12);
            float4 e1 = *(const float4*)(lds + t * 12 + 4);
            float hA = bA, hB = bB;
            hA = fmaf(e0.y, wA0, hA); hB = fmaf(e0.y, wB0, hB);
            hA = fmaf(e0.z, wA1, hA); hB = fmaf(e0.z, wB1, hB);
            hA = fmaf(e0.w, wA2, hA); hB = fmaf(e0.w, wB2, hB);
            hA = fmaf(e1.x, wA3, hA); hB = fmaf(e1.x, wB3, hB);
            hA = fmaf(e1.y, wA4, hA); hB = fmaf(e1.y, wB4, hB);
            hA = fmaf(e1.z, wA5, hA); hB = fmaf(e1.z, wB5, hB);
            hA = fmaxf(hA, 0.f); hB = fmaxf(hB, 0.f);
            accA = fmaf(e0.x, hA, accA); accB = fmaf(e0.x, hB, accB);
        }
    }
    float dn = xagg8[(size_t)n * 8];
    agg[(size_t)n * HID + kA] = dn * accA;
    agg[(size_t)n * HID + kB] = dn * accB;
}

// ---------------------------------------------------------------------------
// K_dense2: h2 = relu(agg @ w_gcn + b_gcn); out = h2 @ w_out + b_out
#define NPB 32
#define HSTR (NPB + 4)
__global__ __launch_bounds__(128) void k_dense2(
    const float* __restrict__ agg, const float* __restrict__ w_gcn,
    const float* __restrict__ b_gcn, const float* __restrict__ w_out,
    const float* __restrict__ b_out, float* __restrict__ out)
{
    __shared__ float hsT[HID][HSTR];
    __shared__ float red[2][64];
    int n0 = blockIdx.x * NPB;
    int tid = threadIdx.x;

#pragma unroll
    for (int r = 0; r < NPB; ++r)
        hsT[tid][r] = agg[(size_t)(n0 + r) * HID + tid];
    __syncthreads();

    float acc[NPB];
#pragma unroll
    for (int r = 0; r < NPB; ++r) acc[r] = 0.f;
    for (int i = 0; i < HID; ++i) {
        float wv = w_gcn[i * HID + tid];
        const float4* hp = (const float4*)&hsT[i][0];
#pragma unroll
        for (int r4 = 0; r4 < NPB / 4; ++r4) {
            float4 hv = hp[r4];
            acc[r4 * 4 + 0] += hv.x * wv;
            acc[r4 * 4 + 1] += hv.y * wv;
            acc[r4 * 4 + 2] += hv.z * wv;
            acc[r4 * 4 + 3] += hv.w * wv;
        }
    }
    __syncthreads();

    float b = b_gcn[tid];
#pragma unroll
    for (int r = 0; r < NPB; ++r)
        hsT[tid][r] = fmaxf(acc[r] + b, 0.f);   // h2, transposed
    __syncthreads();

    int r = tid & 31, o = (tid >> 5) & 1, half = tid >> 6;
    float v = 0.f;
    for (int k = half * 64; k < half * 64 + 64; ++k)
        v += hsT[k][r] * w_out[k * 2 + o];
    red[half][tid & 63] = v;
    __syncthreads();
    if (tid < 64) {
        float t = red[0][tid] + red[1][tid];
        int rr = tid & 31, oo = tid >> 5;
        out[(size_t)(n0 + rr) * 2 + oo] = t + b_out[oo];
    }
}

// ---------------------------------------------------------------------------
__global__ __launch_bounds__(256) void k_copy_ei(
    const int* __restrict__ ei, float* __restrict__ out_ei)
{
    int i = blockIdx.x * 256 + threadIdx.x;
    if (i < 2 * N_EDGES) out_ei[i] = (float)ei[i];
}

// ---------------------------------------------------------------------------
extern "C" void kernel_launch(void* const* d_in, const int* in_sizes, int n_in,
                              void* d_out, int out_size, void* d_ws, size_t ws_size,
                              hipStream_t stream)
{
    const float* x        = (const float*)d_in[0];
    const int*   ei       = (const int*)d_in[1];
    const float* ew       = (const float*)d_in[2];
    const float* w_gat    = (const float*)d_in[3];
    const float* att_src  = (const float*)d_in[4];
    const float* att_dst  = (const float*)d_in[5];
    const float* w_edge   = (const float*)d_in[6];
    const float* att_edge = (const float*)d_in[7];
    const float* b_gat    = (const float*)d_in[8];
    const float* w_gcn    = (const float*)d_in[9];
    const float* b_gcn    = (const float*)d_in[10];
    const float* w_out    = (const float*)d_in[11];
    const float* b_out    = (const float*)d_in[12];

    const int* src = ei;
    const int* dst = ei + N_EDGES;

    float* out_head  = (float*)d_out;
    float* out_ei    = out_head + 2 * N_NODES;
    float* out_alpha = out_ei + 2 * N_EDGES;

    char* ws = (char*)d_ws;
    size_t o = 0;
    auto alloc = [&](size_t bytes) -> char* {
        char* p = ws + o;
        o = (o + bytes + 255) & ~(size_t)255;
        return p;
    };
    float* agg    = (float*)alloc((size_t)N_NODES * HID * 4);   // 51.2 MB
    uint2* rec    = (uint2*)alloc((size_t)N_EDGES * 8);         // 12.8 MB
    uint2* sa_srt = (uint2*)alloc((size_t)N_EDGES * 8);         // 12.8 MB
    float* p_arr  = (float*)alloc((size_t)N_EDGES * 4);         // 6.4 MB
    float* xagg8  = (float*)alloc((size_t)N_NODES * 8 * 4);     // 3.2 MB
    int*   histG  = (int*)alloc((size_t)NHIST * 4);             // 0.63 MB
    int*   incl   = (int*)alloc((size_t)NHIST * 4);
    int*   offP   = (int*)alloc((size_t)(NHIST + 1) * 4);
    float* a_src  = (float*)alloc(N_NODES * 4);
    float* a_dst  = (float*)alloc(N_NODES * 4);
    float* denomG = (float*)alloc(N_NODES * 4);
    int*   off    = (int*)alloc((N_NODES + 1) * 4);
    int*   bsums  = (int*)alloc(512 * 4);
    int*   boffs  = (int*)alloc(512 * 4);
    float* w_as   = (float*)alloc(D_IN * 4);
    float* w_ad   = (float*)alloc(D_IN * 4);
    float* dotwe  = (float*)alloc(4);
    (void)ws_size; (void)out_size; (void)n_in; (void)in_sizes;

    const int NB_NODE = (N_NODES + 255) / 256;          // 391
    const int NB_EDGE = (N_EDGES + 255) / 256;          // 6250
    const int NB_SCANP = (NHIST + 511) / 512;           // 306

    k_prep<<<1, 128, 0, stream>>>(w_gat, att_src, att_dst, w_edge, att_edge,
                                  w_as, w_ad, dotwe);
    k_asrc<<<NB_NODE, 256, 0, stream>>>(x, w_as, w_ad, a_src, a_dst);
    k_hist<<<NBLK_P, 256, 0, stream>>>(dst, histG);
    k_scan1<<<NB_SCANP, 512, 0, stream>>>(histG, incl, bsums, NHIST);
    k_scan2<<<1, 512, 0, stream>>>(bsums, boffs, NB_SCANP);
    k_scan3<<<NB_SCANP, 512, 0, stream>>>(histG, incl, boffs, offP, NHIST);
    k_part<<<NBLK_P, 256, 0, stream>>>(src, dst, ew, a_src, a_dst, dotwe,
                                       offP, p_arr, rec);
    k_s2<<<NBKT, 256, 0, stream>>>(offP, rec, x, sa_srt, xagg8, denomG, off);
    k_alpha<<<NB_EDGE, 256, 0, stream>>>(p_arr, dst, denomG, out_alpha);
    k_gcn_gather<<<N_NODES / 4, 256, 0, stream>>>(
        sa_srt, off, xagg8, w_gat, b_gat, agg);
    k_dense2<<<N_NODES / NPB, 128, 0, stream>>>(
        agg, w_gcn, b_gcn, w_out, b_out, out_head);
    k_copy_ei<<<(2 * N_EDGES + 255) / 256, 256, 0, stream>>>(ei, out_ei);
}

// Round 7
// 294.712 us; speedup vs baseline: 1.6125x; 1.0450x over previous
//
#include <hip/hip_runtime.h>
#include <hip/hip_bf16.h>
#include <math.h>

#define N_NODES 100000
#define N_EDGES 1600000
#define HID 128
#define D_IN 6
#define NEG_SLOPE 0.2f

#define NB_BKT 128                       // nodes per bucket
#define NBKT 782                         // ceil(N_NODES / NB_BKT)
#define NBLK_P 200                       // partition blocks
#define EPB ((N_EDGES + NBLK_P - 1) / NBLK_P)   // 8000 edges per partition block
#define NHIST (NBKT * NBLK_P)            // 156400
#define S2_CAP 3072                      // max edges per bucket (mean 2048, +22 sigma)

// ---------------------------------------------------------------------------
// K_prep (1 block): w_as = w_gat@att_src (6), w_ad = w_gat@att_dst (6),
// dotwe = w_edge . att_edge
__global__ __launch_bounds__(128) void k_prep(
    const float* __restrict__ w_gat, const float* __restrict__ att_src,
    const float* __restrict__ att_dst, const float* __restrict__ w_edge,
    const float* __restrict__ att_edge, float* __restrict__ w_as,
    float* __restrict__ w_ad, float* __restrict__ dotwe)
{
    int tid = threadIdx.x;
    __shared__ float red[4];
    float as = att_src[tid], ad = att_dst[tid];

    float v = w_edge[tid] * att_edge[tid];
    for (int o = 32; o; o >>= 1) v += __shfl_down(v, o);
    if ((tid & 63) == 0) red[tid >> 6] = v;
    __syncthreads();
    if (tid == 0) dotwe[0] = red[0] + red[1];

#pragma unroll
    for (int i = 0; i < D_IN; ++i) {
        float wv = w_gat[i * HID + tid];
        float v1 = wv * as, v2 = wv * ad;
        for (int o = 32; o; o >>= 1) {
            v1 += __shfl_down(v1, o);
            v2 += __shfl_down(v2, o);
        }
        __syncthreads();
        if ((tid & 63) == 0) { red[(tid >> 6) * 2] = v1; red[(tid >> 6) * 2 + 1] = v2; }
        __syncthreads();
        if (tid == 0) { w_as[i] = red[0] + red[2]; w_ad[i] = red[1] + red[3]; }
    }
}

// ---------------------------------------------------------------------------
__global__ __launch_bounds__(256) void k_asrc(
    const float* __restrict__ x, const float* __restrict__ w_as,
    const float* __restrict__ w_ad, float* __restrict__ a_src,
    float* __restrict__ a_dst)
{
    int n = blockIdx.x * 256 + threadIdx.x;
    if (n >= N_NODES) return;
    float s0 = 0.f, s1 = 0.f;
#pragma unroll
    for (int i = 0; i < D_IN; ++i) {
        float xv = x[n * D_IN + i];
        s0 += xv * w_as[i];
        s1 += xv * w_ad[i];
    }
    a_src[n] = s0;
    a_dst[n] = s1;
}

// ---------------------------------------------------------------------------
// K_hist: per-block LDS histogram over dst-buckets (no device atomics)
__global__ __launch_bounds__(256) void k_hist(
    const int* __restrict__ dst, int* __restrict__ histG)
{
    __shared__ int h[NBKT];
    for (int b = threadIdx.x; b < NBKT; b += 256) h[b] = 0;
    __syncthreads();
    int e0 = blockIdx.x * EPB, e1 = min(e0 + EPB, N_EDGES);
    for (int e = e0 + threadIdx.x; e < e1; e += 256)
        atomicAdd(&h[dst[e] >> 7], 1);           // LDS atomic (CU-local)
    __syncthreads();
    for (int b = threadIdx.x; b < NBKT; b += 256)
        histG[b * NBLK_P + blockIdx.x] = h[b];   // bucket-major layout
}

// ---------------------------------------------------------------------------
// generic exclusive scan (3 kernels, 512-thread blocks), n arbitrary
__global__ __launch_bounds__(512) void k_scan1(
    const int* __restrict__ in, int* __restrict__ incl, int* __restrict__ bsums,
    int n)
{
    __shared__ int s[512];
    int tid = threadIdx.x;
    int i = blockIdx.x * 512 + tid;
    int v = (i < n) ? in[i] : 0;
    s[tid] = v;
    __syncthreads();
    for (int o = 1; o < 512; o <<= 1) {
        int t = (tid >= o) ? s[tid - o] : 0;
        __syncthreads();
        s[tid] += t;
        __syncthreads();
    }
    if (i < n) incl[i] = s[tid];
    if (tid == 511) bsums[blockIdx.x] = s[511];
}

__global__ __launch_bounds__(512) void k_scan2(
    const int* __restrict__ bsums, int* __restrict__ boffs, int nb)
{
    __shared__ int s[512];
    int tid = threadIdx.x;
    int v = (tid < nb) ? bsums[tid] : 0;
    s[tid] = v;
    __syncthreads();
    for (int o = 1; o < 512; o <<= 1) {
        int t = (tid >= o) ? s[tid - o] : 0;
        __syncthreads();
        s[tid] += t;
        __syncthreads();
    }
    if (tid < nb) boffs[tid] = s[tid] - v;  // exclusive
}

__global__ __launch_bounds__(512) void k_scan3(
    const int* __restrict__ in, const int* __restrict__ incl,
    const int* __restrict__ boffs, int* __restrict__ off, int n)
{
    int i = blockIdx.x * 512 + threadIdx.x;
    if (i < n) {
        int b = boffs[blockIdx.x];
        off[i] = b + incl[i] - in[i];
        if (i == n - 1) off[n] = b + incl[i];
    }
}

// ---------------------------------------------------------------------------
// K_part: stable partition into dst-buckets. Each (block,bucket) writes into
// its exclusive range [offP[b*200+blk], ...) via an LDS cursor -> no device
// atomics; block-private regions stay L2-resident (low write-amp).
// Also computes p = exp(leaky(logit)) and stores p_arr (original order).
__global__ __launch_bounds__(256) void k_part(
    const int* __restrict__ src, const int* __restrict__ dst,
    const float* __restrict__ ew, const float* __restrict__ a_src,
    const float* __restrict__ a_dst, const float* __restrict__ dotwe,
    const int* __restrict__ offP, float* __restrict__ p_arr,
    uint2* __restrict__ rec)
{
    __shared__ int curs[NBKT];
    for (int b = threadIdx.x; b < NBKT; b += 256)
        curs[b] = offP[b * NBLK_P + blockIdx.x];
    __syncthreads();
    float dw = dotwe[0];
    int e0 = blockIdx.x * EPB, e1 = min(e0 + EPB, N_EDGES);
    for (int e = e0 + threadIdx.x; e < e1; e += 256) {
        int d = dst[e], s = src[e];
        float lg = a_src[s] + a_dst[d] + dw * ew[e];
        lg = (lg >= 0.f) ? lg : NEG_SLOPE * lg;
        float p = __expf(lg);
        p_arr[e] = p;
        int pos = atomicAdd(&curs[d >> 7], 1);   // LDS atomic
        rec[pos] = make_uint2(((unsigned)(d & 127) << 17) | (unsigned)s,
                              __float_as_uint(p));
    }
}

// ---------------------------------------------------------------------------
// K_s2: one block per bucket. LDS counting-sort (local bases via LDS scan),
// per-node denom, alpha normalize, coalesced CSR writeout, xagg, off, denomG.
__global__ __launch_bounds__(256) void k_s2(
    const int* __restrict__ offP, const uint2* __restrict__ rec,
    const float* __restrict__ x, uint2* __restrict__ sa_srt,
    float* __restrict__ xagg8, float* __restrict__ denomG,
    int* __restrict__ off)
{
    __shared__ uint2 srt[S2_CAP];
    __shared__ int cntL[NB_BKT], fillL[NB_BKT], baseL[NB_BKT + 1];
    __shared__ int sc[NB_BKT];
    __shared__ float rden[NB_BKT];
    int b = blockIdx.x, tid = threadIdx.x;
    int g0 = offP[b * NBLK_P];
    int g1 = offP[(b + 1) * NBLK_P];     // b==NBKT-1 -> offP[NHIST] == N_EDGES
    int len = min(g1 - g0, S2_CAP);

    if (tid < NB_BKT) { cntL[tid] = 0; fillL[tid] = 0; }
    __syncthreads();

    // pass 1: count (records re-read from L2)
    for (int i = tid; i < len; i += 256)
        atomicAdd(&cntL[rec[g0 + i].x >> 17], 1);
    __syncthreads();

    // LDS scan over 128 counts -> baseL (exclusive)
    {
        int v = (tid < NB_BKT) ? cntL[tid] : 0;
        if (tid < NB_BKT) sc[tid] = v;
        __syncthreads();
        for (int o = 1; o < NB_BKT; o <<= 1) {
            int t = (tid >= o && tid < NB_BKT) ? sc[tid - o] : 0;
            __syncthreads();
            if (tid < NB_BKT) sc[tid] += t;
            __syncthreads();
        }
        if (tid < NB_BKT) baseL[tid + 1] = sc[tid];
        if (tid == 0) baseL[0] = 0;
    }
    __syncthreads();

    // pass 2: place into sorted LDS order
    for (int i = tid; i < len; i += 256) {
        uint2 r = rec[g0 + i];
        int dl = r.x >> 17;
        int p = baseL[dl] + atomicAdd(&fillL[dl], 1);
        if (p < S2_CAP) srt[p] = r;
    }
    __syncthreads();

    // per-node denom
    if (tid < NB_BKT) {
        int s0 = baseL[tid], s1 = baseL[tid + 1];
        float dsum = 0.f;
        for (int j = s0; j < s1; ++j) dsum += __uint_as_float(srt[j].y);
        int n = b * NB_BKT + tid;
        if (n < N_NODES) denomG[n] = dsum;
        rden[tid] = 1.0f / fmaxf(dsum, 1e-16f);
    }
    __syncthreads();

    // normalize alpha in LDS + coalesced CSR writeout {src, alpha}
    for (int i = tid; i < len; i += 256) {
        uint2 r = srt[i];
        int dl = r.x >> 17;
        float a = __uint_as_float(r.y) * rden[dl];
        srt[i].y = __float_as_uint(a);
        sa_srt[g0 + i] = make_uint2(r.x & 0x1FFFFu, __float_as_uint(a));
    }
    __syncthreads();

    // xagg (6-dim weighted x sum) + off
    if (tid < NB_BKT) {
        int n = b * NB_BKT + tid;
        if (n < N_NODES) {
            int s0 = baseL[tid], s1 = baseL[tid + 1];
            float ax0 = 0, ax1 = 0, ax2 = 0, ax3 = 0, ax4 = 0, ax5 = 0;
            for (int j = s0; j < s1; ++j) {
                uint2 r = srt[j];
                float a = __uint_as_float(r.y);
                const float2* xp = (const float2*)(x + (size_t)(r.x & 0x1FFFFu) * D_IN);
                float2 q0 = xp[0], q1 = xp[1], q2 = xp[2];
                ax0 += a * q0.x; ax1 += a * q0.y; ax2 += a * q1.x;
                ax3 += a * q1.y; ax4 += a * q2.x; ax5 += a * q2.y;
            }
            float dv = (s1 > s0) ? 1.0f : 0.0f;   // sum(alpha)=1 -> dinv=1
            float* xo = xagg8 + (size_t)n * 8;
            float4 lo = {dv, ax0, ax1, ax2};
            float4 hi = {ax3, ax4, ax5, 0.f};
            *(float4*)xo = lo;
            *(float4*)(xo + 4) = hi;
            off[n] = g0 + s0;
        }
    }
    if (b == NBKT - 1 && tid == 0) off[N_NODES] = g1;
}

// ---------------------------------------------------------------------------
// K_alpha: original-order alpha output (coalesced; denom gathered, L3-resident)
__global__ __launch_bounds__(256) void k_alpha(
    const float* __restrict__ p_arr, const int* __restrict__ dst,
    const float* __restrict__ denomG, float* __restrict__ alpha_out)
{
    int e = blockIdx.x * 256 + threadIdx.x;
    if (e >= N_EDGES) return;
    alpha_out[e] = p_arr[e] / fmaxf(denomG[dst[e]], 1e-16f);
}

// ---------------------------------------------------------------------------
// K_gcn_gather (2-phase): 4 nodes/block.
// P1: lane-per-edge parallel gather of {dinv_s*alpha, xagg[0..5]} -> LDS.
// P2: wave-per-node, 2 features/lane, broadcast ds_read_b128, per-feature acc.
#define GCAP 128
__global__ __launch_bounds__(256) void k_gcn_gather(
    const uint2* __restrict__ sa_srt, const int* __restrict__ off,
    const float* __restrict__ xagg8, const float* __restrict__ w_gat,
    const float* __restrict__ b_gat, float* __restrict__ agg)
{
    __shared__ float lds[GCAP * 12];
    int tid = threadIdx.x;
    int n0 = blockIdx.x * 4;
    int wid = tid >> 6, l = tid & 63;
    int n = n0 + wid;
    int beg0 = off[n0];
    int total = off[n0 + 4] - beg0;
    int nb = off[n] - beg0, ne = off[n + 1] - beg0;

    int kA = l, kB = l + 64;
    float wA0 = w_gat[0 * HID + kA], wA1 = w_gat[1 * HID + kA], wA2 = w_gat[2 * HID + kA];
    float wA3 = w_gat[3 * HID + kA], wA4 = w_gat[4 * HID + kA], wA5 = w_gat[5 * HID + kA];
    float wB0 = w_gat[0 * HID + kB], wB1 = w_gat[1 * HID + kB], wB2 = w_gat[2 * HID + kB];
    float wB3 = w_gat[3 * HID + kB], wB4 = w_gat[4 * HID + kB], wB5 = w_gat[5 * HID + kB];
    float bA = b_gat[kA], bB = b_gat[kB];
    float accA = 0.f, accB = 0.f;

    for (int base = 0; base < total; base += GCAP) {
        int cnt = min(GCAP, total - base);
        __syncthreads();
        if (tid < cnt) {
            int j = beg0 + base + tid;
            uint2 sa = sa_srt[j];                  // coalesced 8B
            float a = __uint_as_float(sa.y);
            const float4* xp = (const float4*)(xagg8 + (size_t)sa.x * 8);
            float4 lo = xp[0], hi = xp[1];         // {dinv_s,x0,x1,x2},{x3,x4,x5,-}
            float4 w0 = {lo.x * a, lo.y, lo.z, lo.w};
            float4 w1 = {hi.x, hi.y, hi.z, 0.f};
            *(float4*)(lds + tid * 12) = w0;
            *(float4*)(lds + tid * 12 + 4) = w1;
        }
        __syncthreads();
        int lo_t = nb - base; if (lo_t < 0) lo_t = 0;
        int hi_t = ne - base; if (hi_t > cnt) hi_t = cnt;
        for (int t = lo_t; t < hi_t; ++t) {
            float4 e0 = *(const float4*)(lds + t * 12);
            float4 e1 = *(const float4*)(lds + t * 12 + 4);
            float hA = bA, hB = bB;
            hA = fmaf(e0.y, wA0, hA); hB = fmaf(e0.y, wB0, hB);
            hA = fmaf(e0.z, wA1, hA); hB = fmaf(e0.z, wB1, hB);
            hA = fmaf(e0.w, wA2, hA); hB = fmaf(e0.w, wB2, hB);
            hA = fmaf(e1.x, wA3, hA); hB = fmaf(e1.x, wB3, hB);
            hA = fmaf(e1.y, wA4, hA); hB = fmaf(e1.y, wB4, hB);
            hA = fmaf(e1.z, wA5, hA); hB = fmaf(e1.z, wB5, hB);
            hA = fmaxf(hA, 0.f); hB = fmaxf(hB, 0.f);
            accA = fmaf(e0.x, hA, accA); accB = fmaf(e0.x, hB, accB);
        }
    }
    float dn = xagg8[(size_t)n * 8];
    agg[(size_t)n * HID + kA] = dn * accA;
    agg[(size_t)n * HID + kB] = dn * accB;
}

// ---------------------------------------------------------------------------
// K_dense2 (register-tiled): h2 = relu(agg @ w_gcn + b_gcn); out = h2 @ w_out
// + b_out. 32 nodes per 128-thread block. Per thread: 4 rows x 8 cols tile ->
// per i: 1 broadcast ds_read_b128 + 8 coalesced L2 w-loads + 32 FMA
// (LDS:VALU issue 12:64 cyc -> VALU-bound). Epilogue fully in registers with
// 16-lane shfl_xor tree (no LDS round-trip, no serial 64-iter loop).
#define NPB 32
#define HSTR (NPB + 4)
__global__ __launch_bounds__(128) void k_dense2(
    const float* __restrict__ agg, const float* __restrict__ w_gcn,
    const float* __restrict__ b_gcn, const float* __restrict__ w_out,
    const float* __restrict__ b_out, float* __restrict__ out)
{
    __shared__ float hT[HID][HSTR];   // hT[k][r] = agg[n0+r][k], stride 36
    int tid = threadIdx.x;
    int n0 = blockIdx.x * NPB;

#pragma unroll
    for (int r = 0; r < NPB; ++r)
        hT[tid][r] = agg[(size_t)(n0 + r) * HID + tid];
    __syncthreads();

    int c0 = tid & 15;           // cols c0 + 16*j, j=0..7
    int r0 = (tid >> 4) * 4;     // rows r0..r0+3

    float acc[4][8];
#pragma unroll
    for (int r = 0; r < 4; ++r)
#pragma unroll
        for (int j = 0; j < 8; ++j) acc[r][j] = 0.f;

    const float* wp = w_gcn + c0;
#pragma unroll 2
    for (int i = 0; i < HID; ++i) {
        float4 hv = *(const float4*)&hT[i][r0];
        float w[8];
#pragma unroll
        for (int j = 0; j < 8; ++j) w[j] = wp[i * HID + 16 * j];
#pragma unroll
        for (int j = 0; j < 8; ++j) {
            acc[0][j] = fmaf(hv.x, w[j], acc[0][j]);
            acc[1][j] = fmaf(hv.y, w[j], acc[1][j]);
            acc[2][j] = fmaf(hv.z, w[j], acc[2][j]);
            acc[3][j] = fmaf(hv.w, w[j], acc[3][j]);
        }
    }

    // bias + relu + output head partials (cols owned by this thread)
    float po[4][2];
#pragma unroll
    for (int r = 0; r < 4; ++r) { po[r][0] = 0.f; po[r][1] = 0.f; }
#pragma unroll
    for (int j = 0; j < 8; ++j) {
        int c = c0 + 16 * j;
        float b = b_gcn[c];
        float w0 = w_out[c * 2 + 0], w1 = w_out[c * 2 + 1];
#pragma unroll
        for (int r = 0; r < 4; ++r) {
            float h2 = fmaxf(acc[r][j] + b, 0.f);
            po[r][0] = fmaf(h2, w0, po[r][0]);
            po[r][1] = fmaf(h2, w1, po[r][1]);
        }
    }

    // reduce across the 16 lanes covering all 128 cols (xor masks stay in-group)
#pragma unroll
    for (int r = 0; r < 4; ++r)
#pragma unroll
        for (int o = 0; o < 2; ++o) {
            float v = po[r][o];
            v += __shfl_xor(v, 1);
            v += __shfl_xor(v, 2);
            v += __shfl_xor(v, 4);
            v += __shfl_xor(v, 8);
            po[r][o] = v;
        }
    if ((tid & 15) == 0) {
        float b0 = b_out[0], b1 = b_out[1];
#pragma unroll
        for (int r = 0; r < 4; ++r) {
            out[(size_t)(n0 + r0 + r) * 2 + 0] = po[r][0] + b0;
            out[(size_t)(n0 + r0 + r) * 2 + 1] = po[r][1] + b1;
        }
    }
}

// ---------------------------------------------------------------------------
// K_copy_ei: edge_index (int) -> float output, vectorized int4 -> float4
__global__ __launch_bounds__(256) void k_copy_ei(
    const int* __restrict__ ei, float* __restrict__ out_ei)
{
    int i = blockIdx.x * 256 + threadIdx.x;   // quad index
    if (i < (2 * N_EDGES) / 4) {
        int4 v = ((const int4*)ei)[i];
        float4 f = {(float)v.x, (float)v.y, (float)v.z, (float)v.w};
        ((float4*)out_ei)[i] = f;
    }
}

// ---------------------------------------------------------------------------
extern "C" void kernel_launch(void* const* d_in, const int* in_sizes, int n_in,
                              void* d_out, int out_size, void* d_ws, size_t ws_size,
                              hipStream_t stream)
{
    const float* x        = (const float*)d_in[0];
    const int*   ei       = (const int*)d_in[1];
    const float* ew       = (const float*)d_in[2];
    const float* w_gat    = (const float*)d_in[3];
    const float* att_src  = (const float*)d_in[4];
    const float* att_dst  = (const float*)d_in[5];
    const float* w_edge   = (const float*)d_in[6];
    const float* att_edge = (const float*)d_in[7];
    const float* b_gat    = (const float*)d_in[8];
    const float* w_gcn    = (const float*)d_in[9];
    const float* b_gcn    = (const float*)d_in[10];
    const float* w_out    = (const float*)d_in[11];
    const float* b_out    = (const float*)d_in[12];

    const int* src = ei;
    const int* dst = ei + N_EDGES;

    float* out_head  = (float*)d_out;
    float* out_ei    = out_head + 2 * N_NODES;
    float* out_alpha = out_ei + 2 * N_EDGES;

    char* ws = (char*)d_ws;
    size_t o = 0;
    auto alloc = [&](size_t bytes) -> char* {
        char* p = ws + o;
        o = (o + bytes + 255) & ~(size_t)255;
        return p;
    };
    float* agg    = (float*)alloc((size_t)N_NODES * HID * 4);   // 51.2 MB
    uint2* rec    = (uint2*)alloc((size_t)N_EDGES * 8);         // 12.8 MB
    uint2* sa_srt = (uint2*)alloc((size_t)N_EDGES * 8);         // 12.8 MB
    float* p_arr  = (float*)alloc((size_t)N_EDGES * 4);         // 6.4 MB
    float* xagg8  = (float*)alloc((size_t)N_NODES * 8 * 4);     // 3.2 MB
    int*   histG  = (int*)alloc((size_t)NHIST * 4);             // 0.63 MB
    int*   incl   = (int*)alloc((size_t)NHIST * 4);
    int*   offP   = (int*)alloc((size_t)(NHIST + 1) * 4);
    float* a_src  = (float*)alloc(N_NODES * 4);
    float* a_dst  = (float*)alloc(N_NODES * 4);
    float* denomG = (float*)alloc(N_NODES * 4);
    int*   off    = (int*)alloc((N_NODES + 1) * 4);
    int*   bsums  = (int*)alloc(512 * 4);
    int*   boffs  = (int*)alloc(512 * 4);
    float* w_as   = (float*)alloc(D_IN * 4);
    float* w_ad   = (float*)alloc(D_IN * 4);
    float* dotwe  = (float*)alloc(4);
    (void)ws_size; (void)out_size; (void)n_in; (void)in_sizes;

    const int NB_NODE = (N_NODES + 255) / 256;          // 391
    const int NB_EDGE = (N_EDGES + 255) / 256;          // 6250
    const int NB_SCANP = (NHIST + 511) / 512;           // 306

    k_prep<<<1, 128, 0, stream>>>(w_gat, att_src, att_dst, w_edge, att_edge,
                                  w_as, w_ad, dotwe);
    k_asrc<<<NB_NODE, 256, 0, stream>>>(x, w_as, w_ad, a_src, a_dst);
    k_hist<<<NBLK_P, 256, 0, stream>>>(dst, histG);
    k_scan1<<<NB_SCANP, 512, 0, stream>>>(histG, incl, bsums, NHIST);
    k_scan2<<<1, 512, 0, stream>>>(bsums, boffs, NB_SCANP);
    k_scan3<<<NB_SCANP, 512, 0, stream>>>(histG, incl, boffs, offP, NHIST);
    k_part<<<NBLK_P, 256, 0, stream>>>(src, dst, ew, a_src, a_dst, dotwe,
                                       offP, p_arr, rec);
    k_s2<<<NBKT, 256, 0, stream>>>(offP, rec, x, sa_srt, xagg8, denomG, off);
    k_alpha<<<NB_EDGE, 256, 0, stream>>>(p_arr, dst, denomG, out_alpha);
    k_gcn_gather<<<N_NODES / 4, 256, 0, stream>>>(
        sa_srt, off, xagg8, w_gat, b_gat, agg);
    k_dense2<<<N_NODES / NPB, 128, 0, stream>>>(
        agg, w_gcn, b_gcn, w_out, b_out, out_head);
    k_copy_ei<<<(2 * N_EDGES) / 4 / 256 + 1, 256, 0, stream>>>(ei, out_ei);
}